// Round 2
// baseline (14565.985 us; speedup 1.0000x reference)
//
#include <hip/hip_runtime.h>
#include <hip/hip_bf16.h>

typedef __attribute__((ext_vector_type(8))) short short8;
typedef __attribute__((ext_vector_type(4))) float f32x4;

#define HID 512
#define T_STEPS 90
#define RBLK 64
#define NBLK 256  /* 16384 rows / 64 */

__device__ __forceinline__ unsigned short f2bf(float x) {
  unsigned int u = __float_as_uint(x);
  u = u + 0x7FFFu + ((u >> 16) & 1u);   // round-to-nearest-even
  return (unsigned short)(u >> 16);
}
__device__ __forceinline__ float bf2f(unsigned short s) {
  return __uint_as_float(((unsigned int)s) << 16);
}

__device__ __forceinline__ unsigned int cvtpk(float a, float b) {
  unsigned int r;
  asm("v_cvt_pk_bf16_f32 %0, %1, %2" : "=v"(r) : "v"(a), "v"(b));
  return r;
}
// pack 8 consecutive fp32 (two f32x4) into a bf16 short8 MFMA fragment (RNE)
__device__ __forceinline__ short8 pack8(f32x4 a, f32x4 b) {
  union { unsigned int u[4]; short8 s; } z;
  z.u[0] = cvtpk(a[0], a[1]); z.u[1] = cvtpk(a[2], a[3]);
  z.u[2] = cvtpk(b[0], b[1]); z.u[3] = cvtpk(b[2], b[3]);
  return z.s;
}

// branch-free exact-erf gelu (A&S 7.1.26, |err_erf| <= 1.5e-7)
__device__ __forceinline__ float gelu_f(float x) {
  float u = fabsf(x) * 0.70710678118654752f;
  float d = fmaf(0.3275911f, u, 1.0f);
  float t; asm("v_rcp_f32 %0, %1" : "=v"(t) : "v"(d));
  float poly = t * (0.254829592f + t * (-0.284496736f + t * (1.421413741f +
               t * (-1.453152027f + t * 1.061405429f))));
  float m = -u * u * 1.44269504088896f;
  float ex; asm("v_exp_f32 %0, %1" : "=v"(ex) : "v"(m));
  float e = 1.0f - poly * ex;       // erf(|x|/sqrt2)
  e = copysignf(e, x);
  return 0.5f * x * (1.0f + e);
}

// corr[t][o] = bout[o] - sum_h pos[t+1][h] * bf16(Wout[o][h])   (t<89; corr[89][o]=bout[o])
__global__ void prep_corr(const float* __restrict__ pos, const float* __restrict__ bout,
                          const float* __restrict__ Wout, float* __restrict__ corr) {
  int i = blockIdx.x * blockDim.x + threadIdx.x;
  if (i >= T_STEPS * 16) return;
  int t = i >> 4, o = i & 15;
  float s = 0.f;
  if (t < T_STEPS - 1) {
    const float* pe = pos + (t + 1) * HID;
    for (int h = 0; h < HID; ++h) s += pe[h] * bf2f(f2bf(Wout[o * HID + h]));
  }
  corr[i] = bout[o] - s;
}

// One 32-col half-GEMM over K=512: acc[mt][j] += A(lds) * W^T rows [Wrow0, Wrow1].
// W is fp32 [out][K] (native B^T layout), converted to bf16 in-regs.
// Depth-2 prefetch of B fragments (3 rotating buffers, fully static after unroll).
__device__ __forceinline__ void gemm_half(const unsigned short* Alds,
                                          const float* __restrict__ Wrow0,
                                          const float* __restrict__ Wrow1,
                                          f32x4 (&acc)[4][2],
                                          const int abase, const int axor) {
  f32x4 pre[3][4];
#pragma unroll
  for (int d = 0; d < 2; ++d) {
    pre[d][0] = *(const f32x4*)(Wrow0 + d * 32);
    pre[d][1] = *(const f32x4*)(Wrow0 + d * 32 + 4);
    pre[d][2] = *(const f32x4*)(Wrow1 + d * 32);
    pre[d][3] = *(const f32x4*)(Wrow1 + d * 32 + 4);
  }
#pragma unroll
  for (int kk = 0; kk < 16; ++kk) {
    if (kk + 2 < 16) {
      const int nx = (kk + 2) % 3;
      pre[nx][0] = *(const f32x4*)(Wrow0 + (kk + 2) * 32);
      pre[nx][1] = *(const f32x4*)(Wrow0 + (kk + 2) * 32 + 4);
      pre[nx][2] = *(const f32x4*)(Wrow1 + (kk + 2) * 32);
      pre[nx][3] = *(const f32x4*)(Wrow1 + (kk + 2) * 32 + 4);
    }
    const int cu = kk % 3;
    short8 b0 = pack8(pre[cu][0], pre[cu][1]);
    short8 b1f = pack8(pre[cu][2], pre[cu][3]);
    short8 af[4];
#pragma unroll
    for (int mt = 0; mt < 4; ++mt)
      af[mt] = *(const short8*)(Alds + (((mt * 8192) + abase + kk * 32) ^ axor));
#pragma unroll
    for (int mt = 0; mt < 4; ++mt) {
      acc[mt][0] = __builtin_amdgcn_mfma_f32_16x16x32_bf16(af[mt], b0, acc[mt][0], 0, 0, 0);
      acc[mt][1] = __builtin_amdgcn_mfma_f32_16x16x32_bf16(af[mt], b1f, acc[mt][1], 0, 0, 0);
    }
  }
}

__global__ __launch_bounds__(512, 2) void fd_main(
    const float* __restrict__ latent, const float* __restrict__ b1,
    const float* __restrict__ b2, const float* __restrict__ pos,
    const float* __restrict__ W1, const float* __restrict__ W2,
    const float* __restrict__ Wout, const float* __restrict__ corr,
    float* __restrict__ out) {
  __shared__ __align__(16) unsigned short Xs[RBLK * HID];  // 64KB, X_t bf16 (swizzled)
  __shared__ __align__(16) unsigned short Hs[RBLK * HID];  // 64KB, h bf16 (swizzled)
  const int tid = threadIdx.x;
  const int w = tid >> 6;
  const int l = tid & 63;
  const int lh = l & 15, lq = l >> 4;
  const int cb = w << 6;        // this wave's 64-column slice
  const int rowBase = blockIdx.x * RBLK;
  const int abase = lh * HID + lq * 8;
  const int axor = (lh & 7) << 3;

  float b1v[2][2], b2v[2][2];
#pragma unroll
  for (int nh = 0; nh < 2; ++nh)
#pragma unroll
    for (int j = 0; j < 2; ++j) {
      int col = cb + (nh * 2 + j) * 16 + lh;
      b1v[nh][j] = b1[col];
      b2v[nh][j] = b2[col];
    }

  // state in registers, MFMA C-layout: st[nh][mt][j][r] = state[mt*16+lq*4+r][cb+(nh*2+j)*16+lh]
  f32x4 st[2][4][2];
#pragma unroll
  for (int nh = 0; nh < 2; ++nh)
#pragma unroll
    for (int mt = 0; mt < 4; ++mt)
#pragma unroll
      for (int j = 0; j < 2; ++j)
#pragma unroll
        for (int r = 0; r < 4; ++r)
          st[nh][mt][j][r] =
              latent[(size_t)(rowBase + mt * 16 + lq * 4 + r) * HID + cb + (nh * 2 + j) * 16 + lh];

  // write X_0 = state + pe[0]
#pragma unroll
  for (int nh = 0; nh < 2; ++nh)
#pragma unroll
    for (int j = 0; j < 2; ++j) {
      int col = cb + (nh * 2 + j) * 16 + lh;
      float pev = pos[col];
#pragma unroll
      for (int mt = 0; mt < 4; ++mt)
#pragma unroll
        for (int r = 0; r < 4; ++r) {
          int row = mt * 16 + lq * 4 + r;
          int idx = ((row << 9) + col) ^ ((row & 7) << 3);
          Xs[idx] = f2bf(st[nh][mt][j][r] + pev);
        }
    }
  __syncthreads();

  for (int t = 0; t < T_STEPS; ++t) {
    // ---- GEMM1 (two 32-col halves): a1 = X_t * W1^T + b1; gelu -> Hs ----
#pragma unroll
    for (int nh = 0; nh < 2; ++nh) {
      f32x4 a1[4][2];
#pragma unroll
      for (int mt = 0; mt < 4; ++mt)
#pragma unroll
        for (int j = 0; j < 2; ++j)
          a1[mt][j] = (f32x4){b1v[nh][j], b1v[nh][j], b1v[nh][j], b1v[nh][j]};
      const float* w0 = W1 + (size_t)(cb + nh * 32 + lh) * HID + lq * 8;
      gemm_half(Xs, w0, w0 + 16 * HID, a1, abase, axor);
#pragma unroll
      for (int mt = 0; mt < 4; ++mt)
#pragma unroll
        for (int j = 0; j < 2; ++j) {
          int col = cb + (nh * 2 + j) * 16 + lh;
#pragma unroll
          for (int r = 0; r < 4; ++r) {
            float g = gelu_f(a1[mt][j][r]);
            int row = mt * 16 + lq * 4 + r;
            int idx = ((row << 9) + col) ^ ((row & 7) << 3);
            Hs[idx] = f2bf(g);
          }
        }
    }
    __syncthreads();

    // ---- GEMM2 (two halves): st = st + h * W2^T + b2 (residual accumulates in-place) ----
#pragma unroll
    for (int nh = 0; nh < 2; ++nh) {
#pragma unroll
      for (int mt = 0; mt < 4; ++mt)
#pragma unroll
        for (int j = 0; j < 2; ++j)
          st[nh][mt][j] += b2v[nh][j];
      const float* w0 = W2 + (size_t)(cb + nh * 32 + lh) * HID + lq * 8;
      gemm_half(Hs, w0, w0 + 16 * HID, st[nh], abase, axor);
    }

    // ---- write X_{t+1} = state_t + pe[t+1]  (pe=0 for last step) ----
#pragma unroll
    for (int nh = 0; nh < 2; ++nh)
#pragma unroll
      for (int j = 0; j < 2; ++j) {
        int col = cb + (nh * 2 + j) * 16 + lh;
        float pev = (t < T_STEPS - 1) ? pos[(t + 1) * HID + col] : 0.f;
#pragma unroll
        for (int mt = 0; mt < 4; ++mt)
#pragma unroll
          for (int r = 0; r < 4; ++r) {
            int row = mt * 16 + lq * 4 + r;
            int idx = ((row << 9) + col) ^ ((row & 7) << 3);
            Xs[idx] = f2bf(st[nh][mt][j][r] + pev);
          }
      }
    __syncthreads();

    // ---- out-proj: out_t = X_{t+1} * Wout^T + corr[t]  (waves 0-3, one m-tile each) ----
    if (w < 4) {
      const int mt = w;
      float cv = corr[t * 16 + lh];
      f32x4 ao = {cv, cv, cv, cv};
      const float* wop = Wout + (size_t)lh * HID + lq * 8;
      f32x4 po[3][2];
#pragma unroll
      for (int d = 0; d < 2; ++d) {
        po[d][0] = *(const f32x4*)(wop + d * 32);
        po[d][1] = *(const f32x4*)(wop + d * 32 + 4);
      }
#pragma unroll
      for (int kk = 0; kk < 16; ++kk) {
        if (kk + 2 < 16) {
          const int nx = (kk + 2) % 3;
          po[nx][0] = *(const f32x4*)(wop + (kk + 2) * 32);
          po[nx][1] = *(const f32x4*)(wop + (kk + 2) * 32 + 4);
        }
        short8 bo = pack8(po[kk % 3][0], po[kk % 3][1]);
        short8 af = *(const short8*)(Xs + (((mt * 8192) + abase + kk * 32) ^ axor));
        ao = __builtin_amdgcn_mfma_f32_16x16x32_bf16(af, bo, ao, 0, 0, 0);
      }
#pragma unroll
      for (int r = 0; r < 4; ++r) {
        int row = rowBase + mt * 16 + lq * 4 + r;
        int bb = row >> 8, ss = row & 255;
        out[(size_t)((bb * T_STEPS + t) * 256 + ss) * 16 + lh] = ao[r];
      }
    }
    // no barrier needed here: next write to Xs is after the next barrier.
  }
}

extern "C" void kernel_launch(void* const* d_in, const int* in_sizes, int n_in,
                              void* d_out, int out_size, void* d_ws, size_t ws_size,
                              hipStream_t stream) {
  const float* latent = (const float*)d_in[0];
  const float* W1 = (const float*)d_in[1];
  const float* b1 = (const float*)d_in[2];
  const float* W2 = (const float*)d_in[3];
  const float* b2 = (const float*)d_in[4];
  const float* Wout = (const float*)d_in[5];
  const float* bout = (const float*)d_in[6];
  const float* pos = (const float*)d_in[7];

  float* corr = (float*)d_ws;  // 90*16 floats

  prep_corr<<<6, 256, 0, stream>>>(pos, bout, Wout, corr);
  fd_main<<<NBLK, 512, 0, stream>>>(latent, b1, b2, pos, W1, W2, Wout, corr,
                                    (float*)d_out);
}

// Round 3
// 9817.290 us; speedup vs baseline: 1.4837x; 1.4837x over previous
//
#include <hip/hip_runtime.h>
#include <hip/hip_bf16.h>

typedef __attribute__((ext_vector_type(8))) short short8;
typedef __attribute__((ext_vector_type(4))) float f32x4;

#define HID 512
#define T_STEPS 90
#define RBLK 64
#define NBLK 256  /* 16384 rows / 64 */

__device__ __forceinline__ unsigned short f2bf(float x) {
  unsigned int u = __float_as_uint(x);
  u = u + 0x7FFFu + ((u >> 16) & 1u);   // round-to-nearest-even
  return (unsigned short)(u >> 16);
}
__device__ __forceinline__ float bf2f(unsigned short s) {
  return __uint_as_float(((unsigned int)s) << 16);
}

// branch-free exact-erf gelu (A&S 7.1.26, |err_erf| <= 1.5e-7)
__device__ __forceinline__ float gelu_f(float x) {
  float u = fabsf(x) * 0.70710678118654752f;
  float d = fmaf(0.3275911f, u, 1.0f);
  float t; asm("v_rcp_f32 %0, %1" : "=v"(t) : "v"(d));
  float poly = t * (0.254829592f + t * (-0.284496736f + t * (1.421413741f +
               t * (-1.453152027f + t * 1.061405429f))));
  float m = -u * u * 1.44269504088896f;
  float ex; asm("v_exp_f32 %0, %1" : "=v"(ex) : "v"(m));
  float e = 1.0f - poly * ex;       // erf(|x|/sqrt2)
  e = copysignf(e, x);
  return 0.5f * x * (1.0f + e);
}

// ---- prep: fp32 weights -> bf16 in workspace ----
__global__ void prep_convert(const float* __restrict__ W1, const float* __restrict__ W2,
                             const float* __restrict__ Wout, unsigned short* __restrict__ wbf) {
  int i = blockIdx.x * blockDim.x + threadIdx.x;
  if (i >= 532480) return;
  float v;
  if (i < 262144) v = W1[i];
  else if (i < 524288) v = W2[i - 262144];
  else v = Wout[i - 524288];
  wbf[i] = f2bf(v);
}

// corr[t][o] = bout[o] - sum_h pos[t+1][h] * bf16(Wout[o][h])   (t<89; corr[89][o]=bout[o])
__global__ void prep_corr(const float* __restrict__ pos, const float* __restrict__ bout,
                          const unsigned short* __restrict__ Woutbf, float* __restrict__ corr) {
  int i = blockIdx.x * blockDim.x + threadIdx.x;
  if (i >= T_STEPS * 16) return;
  int t = i >> 4, o = i & 15;
  float s = 0.f;
  if (t < T_STEPS - 1) {
    const float* pe = pos + (t + 1) * HID;
    for (int h = 0; h < HID; ++h) s += pe[h] * bf2f(Woutbf[o * HID + h]);
  }
  corr[i] = bout[o] - s;
}

// one K=512 pass: acc[mt][nt] += A(lds) * W^T; W bf16 [512][512] row-major (B^T layout).
// Depth-3 rotating prefetch of B fragments (4 slots, fully static after unroll).
__device__ __forceinline__ void gemm_tile(const unsigned short* Alds,
                                          const unsigned short* __restrict__ Wbf,
                                          f32x4 (&acc)[4][4],
                                          int cb, int lh, int lq,
                                          const int abase, const int axor) {
  const unsigned short* wp0 = Wbf + (cb + 0 * 16 + lh) * HID + lq * 8;
  const unsigned short* wp1 = Wbf + (cb + 1 * 16 + lh) * HID + lq * 8;
  const unsigned short* wp2 = Wbf + (cb + 2 * 16 + lh) * HID + lq * 8;
  const unsigned short* wp3 = Wbf + (cb + 3 * 16 + lh) * HID + lq * 8;
  short8 buf[4][4];
#pragma unroll
  for (int d = 0; d < 3; ++d) {
    buf[d][0] = *(const short8*)(wp0 + d * 32);
    buf[d][1] = *(const short8*)(wp1 + d * 32);
    buf[d][2] = *(const short8*)(wp2 + d * 32);
    buf[d][3] = *(const short8*)(wp3 + d * 32);
  }
#pragma unroll
  for (int kk = 0; kk < 16; ++kk) {
    if (kk + 3 < 16) {
      const int s = (kk + 3) & 3;
      buf[s][0] = *(const short8*)(wp0 + (kk + 3) * 32);
      buf[s][1] = *(const short8*)(wp1 + (kk + 3) * 32);
      buf[s][2] = *(const short8*)(wp2 + (kk + 3) * 32);
      buf[s][3] = *(const short8*)(wp3 + (kk + 3) * 32);
    }
    const int c = kk & 3;
    short8 af[4];
#pragma unroll
    for (int mt = 0; mt < 4; ++mt)
      af[mt] = *(const short8*)(Alds + (((mt * 8192) + abase + kk * 32) ^ axor));
#pragma unroll
    for (int mt = 0; mt < 4; ++mt)
#pragma unroll
      for (int nt = 0; nt < 4; ++nt)
        acc[mt][nt] = __builtin_amdgcn_mfma_f32_16x16x32_bf16(af[mt], buf[c][nt], acc[mt][nt], 0, 0, 0);
  }
}

__global__ __launch_bounds__(512, 2) void fd_main(
    const float* __restrict__ latent, const float* __restrict__ b1,
    const float* __restrict__ b2, const float* __restrict__ pos,
    const unsigned short* __restrict__ W1bf, const unsigned short* __restrict__ W2bf,
    const unsigned short* __restrict__ Woutbf, const float* __restrict__ corr,
    unsigned int* __restrict__ gbar, float* __restrict__ out) {
  __shared__ __align__(16) unsigned short Xs[RBLK * HID];  // 64KB, X_t bf16 (swizzled)
  __shared__ __align__(16) unsigned short Hs[RBLK * HID];  // 64KB, h bf16 (swizzled)
  const int tid = threadIdx.x;
  const int w = tid >> 6;
  const int l = tid & 63;
  const int lh = l & 15, lq = l >> 4;
  const int cb = w << 6;        // this wave's 64-column slice
  const int cbl = cb + lh;
  const int rowBase = blockIdx.x * RBLK;
  const int abase = lh * HID + lq * 8;
  const int axor = (lh & 7) << 3;

  float b1v[4], b2v[4];
#pragma unroll
  for (int nt = 0; nt < 4; ++nt) { b1v[nt] = b1[cbl + nt * 16]; b2v[nt] = b2[cbl + nt * 16]; }

  // state in registers, MFMA C-layout: st[mt][nt][r] = state[mt*16+lq*4+r][cb+nt*16+lh]
  f32x4 st[4][4];
#pragma unroll
  for (int mt = 0; mt < 4; ++mt)
#pragma unroll
    for (int nt = 0; nt < 4; ++nt) {
#pragma unroll
      for (int r = 0; r < 4; ++r)
        st[mt][nt][r] = latent[(size_t)(rowBase + mt * 16 + lq * 4 + r) * HID + cbl + nt * 16];
    }

  // write X_0 = state + pe[0]
  {
    float pev[4];
#pragma unroll
    for (int nt = 0; nt < 4; ++nt) pev[nt] = pos[cbl + nt * 16];
#pragma unroll
    for (int mt = 0; mt < 4; ++mt)
#pragma unroll
      for (int nt = 0; nt < 4; ++nt)
#pragma unroll
        for (int r = 0; r < 4; ++r) {
          int row = mt * 16 + lq * 4 + r;
          int idx = ((row << 9) + cbl + nt * 16) ^ ((row & 7) << 3);
          Xs[idx] = f2bf(st[mt][nt][r] + pev[nt]);
        }
  }
  __syncthreads();

  const unsigned short* woutp = Woutbf + lh * HID + lq * 8;

  for (int t = 0; t < T_STEPS; ++t) {
    // ---- GEMM1: a1 = X_t * W1^T + b1 ----
    f32x4 a1[4][4];
#pragma unroll
    for (int mt = 0; mt < 4; ++mt)
#pragma unroll
      for (int nt = 0; nt < 4; ++nt)
        a1[mt][nt] = (f32x4){b1v[nt], b1v[nt], b1v[nt], b1v[nt]};
    gemm_tile(Xs, W1bf, a1, cb, lh, lq, abase, axor);

    // ---- gelu -> Hs ----
#pragma unroll
    for (int mt = 0; mt < 4; ++mt)
#pragma unroll
      for (int nt = 0; nt < 4; ++nt)
#pragma unroll
        for (int r = 0; r < 4; ++r) {
          float g = gelu_f(a1[mt][nt][r]);
          int row = mt * 16 + lq * 4 + r;
          int idx = ((row << 9) + cbl + nt * 16) ^ ((row & 7) << 3);
          Hs[idx] = f2bf(g);
        }
    __syncthreads();

    // ---- GEMM2: st = st + h * W2^T + b2  (residual accumulates in-place) ----
#pragma unroll
    for (int mt = 0; mt < 4; ++mt)
#pragma unroll
      for (int nt = 0; nt < 4; ++nt)
        st[mt][nt] += b2v[nt];
    gemm_tile(Hs, W2bf, st, cb, lh, lq, abase, axor);

    // ---- write X_{t+1} = state_t + pe[t+1]  (pe=0 for last step) ----
    {
      float pev[4] = {0.f, 0.f, 0.f, 0.f};
      if (t < T_STEPS - 1) {
#pragma unroll
        for (int nt = 0; nt < 4; ++nt) pev[nt] = pos[(t + 1) * HID + cbl + nt * 16];
      }
#pragma unroll
      for (int mt = 0; mt < 4; ++mt)
#pragma unroll
        for (int nt = 0; nt < 4; ++nt)
#pragma unroll
          for (int r = 0; r < 4; ++r) {
            int row = mt * 16 + lq * 4 + r;
            int idx = ((row << 9) + cbl + nt * 16) ^ ((row & 7) << 3);
            Xs[idx] = f2bf(st[mt][nt][r] + pev[nt]);
          }
    }
    __syncthreads();

    // ---- out-proj (waves 0-3) overlapped with global alignment barrier (wave 7) ----
    if (w < 4) {
      const int mt = w;
      float cv = corr[t * 16 + lh];
      f32x4 ao = {cv, cv, cv, cv};
#pragma unroll
      for (int kk = 0; kk < 16; ++kk) {
        short8 af = *(const short8*)(Xs + (((mt * 8192) + abase + kk * 32) ^ axor));
        short8 bfr = *(const short8*)(woutp + kk * 32);
        ao = __builtin_amdgcn_mfma_f32_16x16x32_bf16(af, bfr, ao, 0, 0, 0);
      }
#pragma unroll
      for (int r = 0; r < 4; ++r) {
        int row = rowBase + mt * 16 + lq * 4 + r;
        int bb = row >> 8, ss = row & 255;
        out[(size_t)((bb * T_STEPS + t) * 256 + ss) * 16 + lh] = ao[r];
      }
    } else if (tid == 448) {
      // Global alignment barrier: monotonic counter; purely a scheduling device
      // (no data crosses it), so relaxed atomics + bounded spin are safe.
      unsigned int target = 256u * (unsigned int)(t + 1);
      __hip_atomic_fetch_add(gbar, 1u, __ATOMIC_RELAXED, __HIP_MEMORY_SCOPE_AGENT);
      for (int p = 0; p < 1000; ++p) {
        unsigned int v = __hip_atomic_fetch_add(gbar, 0u, __ATOMIC_RELAXED, __HIP_MEMORY_SCOPE_AGENT);
        if (v >= target) break;
        __builtin_amdgcn_s_sleep(4);
      }
    }
    __syncthreads();
  }
}

extern "C" void kernel_launch(void* const* d_in, const int* in_sizes, int n_in,
                              void* d_out, int out_size, void* d_ws, size_t ws_size,
                              hipStream_t stream) {
  const float* latent = (const float*)d_in[0];
  const float* W1 = (const float*)d_in[1];
  const float* b1 = (const float*)d_in[2];
  const float* W2 = (const float*)d_in[3];
  const float* b2 = (const float*)d_in[4];
  const float* Wout = (const float*)d_in[5];
  const float* bout = (const float*)d_in[6];
  const float* pos = (const float*)d_in[7];

  unsigned short* wbf = (unsigned short*)d_ws;
  unsigned short* W1bf = wbf;                     // 512*512
  unsigned short* W2bf = wbf + 262144;            // 512*512
  unsigned short* Woutbf = wbf + 524288;          // 16*512
  float* corr = (float*)(wbf + 532480);           // 90*16 floats @ byte 1064960
  unsigned int* gbar = (unsigned int*)((char*)d_ws + 1070720);

  hipMemsetAsync(gbar, 0, 4, stream);  // deterministic per launch/replay
  prep_convert<<<2080, 256, 0, stream>>>(W1, W2, Wout, wbf);
  prep_corr<<<6, 256, 0, stream>>>(pos, bout, Woutbf, corr);
  fd_main<<<NBLK, 512, 0, stream>>>(latent, b1, b2, pos, W1bf, W2bf, Woutbf, corr,
                                    gbar, (float*)d_out);
}

// Round 4
// 8793.424 us; speedup vs baseline: 1.6565x; 1.1164x over previous
//
#include <hip/hip_runtime.h>
#include <hip/hip_bf16.h>

typedef __attribute__((ext_vector_type(8))) short short8;
typedef __attribute__((ext_vector_type(4))) float f32x4;

#define HID 512
#define T_STEPS 90
#define RBLK 64
#define NBLK 256  /* 16384 rows / 64 */

__device__ __forceinline__ unsigned short f2bf(float x) {
  unsigned int u = __float_as_uint(x);
  u = u + 0x7FFFu + ((u >> 16) & 1u);   // round-to-nearest-even
  return (unsigned short)(u >> 16);
}
__device__ __forceinline__ float bf2f(unsigned short s) {
  return __uint_as_float(((unsigned int)s) << 16);
}

// branch-free exact-erf gelu (A&S 7.1.26, |err_erf| <= 1.5e-7)
__device__ __forceinline__ float gelu_f(float x) {
  float u = fabsf(x) * 0.70710678118654752f;
  float d = fmaf(0.3275911f, u, 1.0f);
  float t; asm("v_rcp_f32 %0, %1" : "=v"(t) : "v"(d));
  float poly = t * (0.254829592f + t * (-0.284496736f + t * (1.421413741f +
               t * (-1.453152027f + t * 1.061405429f))));
  float m = -u * u * 1.44269504088896f;
  float ex; asm("v_exp_f32 %0, %1" : "=v"(ex) : "v"(m));
  float e = 1.0f - poly * ex;       // erf(|x|/sqrt2)
  e = copysignf(e, x);
  return 0.5f * x * (1.0f + e);
}

// fire-and-forget 16B global->LDS DMA (L2-warming; LDS content is garbage)
__device__ __forceinline__ void gl_lds16(const void* g, void* lds) {
  __builtin_amdgcn_global_load_lds(
      (const __attribute__((address_space(1))) unsigned int*)g,
      (__attribute__((address_space(3))) unsigned int*)lds, 16, 0, 0);
}

// Warm one 512KB weight matrix into this XCD's L2: 8 hashed 16KB slices,
// 2KB per wave per slice (2 x 1KB wave-DMA). Redundant requests hit/merge in L2.
__device__ __forceinline__ void warm_w(const unsigned short* __restrict__ Wbf,
                                       void* scratch, int bid, int w, int l) {
#pragma unroll
  for (int i = 0; i < 8; ++i) {
    int slice = ((bid >> 3) + i * 13) & 31;
    const char* g = (const char*)Wbf + (size_t)slice * 16384 + w * 2048 + l * 16;
    gl_lds16(g, scratch);
    gl_lds16(g + 1024, scratch);
  }
}

// ---- prep: fp32 weights -> bf16 in workspace ----
__global__ void prep_convert(const float* __restrict__ W1, const float* __restrict__ W2,
                             const float* __restrict__ Wout, unsigned short* __restrict__ wbf) {
  int i = blockIdx.x * blockDim.x + threadIdx.x;
  if (i >= 532480) return;
  float v;
  if (i < 262144) v = W1[i];
  else if (i < 524288) v = W2[i - 262144];
  else v = Wout[i - 524288];
  wbf[i] = f2bf(v);
}

// corr[t][o] = bout[o] - sum_h pos[t+1][h] * bf16(Wout[o][h])   (t<89; corr[89][o]=bout[o])
__global__ void prep_corr(const float* __restrict__ pos, const float* __restrict__ bout,
                          const unsigned short* __restrict__ Woutbf, float* __restrict__ corr) {
  int i = blockIdx.x * blockDim.x + threadIdx.x;
  if (i >= T_STEPS * 16) return;
  int t = i >> 4, o = i & 15;
  float s = 0.f;
  if (t < T_STEPS - 1) {
    const float* pe = pos + (t + 1) * HID;
    for (int h = 0; h < HID; ++h) s += pe[h] * bf2f(Woutbf[o * HID + h]);
  }
  corr[i] = bout[o] - s;
}

// one K=512 pass: acc[mt][nt] += A(lds) * W^T; W bf16 [512][512] row-major (B^T layout).
// Depth-3 rotating prefetch of B fragments (4 slots, fully static after unroll).
__device__ __forceinline__ void gemm_tile(const unsigned short* Alds,
                                          const unsigned short* __restrict__ Wbf,
                                          f32x4 (&acc)[4][4],
                                          int cb, int lh, int lq,
                                          const int abase, const int axor) {
  const unsigned short* wp0 = Wbf + (cb + 0 * 16 + lh) * HID + lq * 8;
  const unsigned short* wp1 = Wbf + (cb + 1 * 16 + lh) * HID + lq * 8;
  const unsigned short* wp2 = Wbf + (cb + 2 * 16 + lh) * HID + lq * 8;
  const unsigned short* wp3 = Wbf + (cb + 3 * 16 + lh) * HID + lq * 8;
  short8 buf[4][4];
#pragma unroll
  for (int d = 0; d < 3; ++d) {
    buf[d][0] = *(const short8*)(wp0 + d * 32);
    buf[d][1] = *(const short8*)(wp1 + d * 32);
    buf[d][2] = *(const short8*)(wp2 + d * 32);
    buf[d][3] = *(const short8*)(wp3 + d * 32);
  }
#pragma unroll
  for (int kk = 0; kk < 16; ++kk) {
    if (kk + 3 < 16) {
      const int s = (kk + 3) & 3;
      buf[s][0] = *(const short8*)(wp0 + (kk + 3) * 32);
      buf[s][1] = *(const short8*)(wp1 + (kk + 3) * 32);
      buf[s][2] = *(const short8*)(wp2 + (kk + 3) * 32);
      buf[s][3] = *(const short8*)(wp3 + (kk + 3) * 32);
    }
    const int c = kk & 3;
    short8 af[4];
#pragma unroll
    for (int mt = 0; mt < 4; ++mt)
      af[mt] = *(const short8*)(Alds + (((mt * 8192) + abase + kk * 32) ^ axor));
#pragma unroll
    for (int mt = 0; mt < 4; ++mt)
#pragma unroll
      for (int nt = 0; nt < 4; ++nt)
        acc[mt][nt] = __builtin_amdgcn_mfma_f32_16x16x32_bf16(af[mt], buf[c][nt], acc[mt][nt], 0, 0, 0);
  }
}

__global__ __launch_bounds__(512, 2) void fd_main(
    const float* __restrict__ latent, const float* __restrict__ b1,
    const float* __restrict__ b2, const float* __restrict__ pos,
    const unsigned short* __restrict__ W1bf, const unsigned short* __restrict__ W2bf,
    const unsigned short* __restrict__ Woutbf, const float* __restrict__ corr,
    unsigned int* __restrict__ gbar, float* __restrict__ out) {
  __shared__ __align__(16) unsigned short Xs[RBLK * HID];  // 64KB, X_t bf16 (swizzled)
  __shared__ __align__(16) unsigned short Hs[RBLK * HID];  // 64KB, h bf16 (swizzled)
  __shared__ __align__(16) unsigned char warm_scratch[1024];  // DMA sink, never read
  const int tid = threadIdx.x;
  const int w = tid >> 6;
  const int l = tid & 63;
  const int lh = l & 15, lq = l >> 4;
  const int cb = w << 6;        // this wave's 64-column slice
  const int cbl = cb + lh;
  const int bid = blockIdx.x;
  const int rowBase = bid * RBLK;
  const int abase = lh * HID + lq * 8;
  const int axor = (lh & 7) << 3;

  float b1v[4], b2v[4];
#pragma unroll
  for (int nt = 0; nt < 4; ++nt) { b1v[nt] = b1[cbl + nt * 16]; b2v[nt] = b2[cbl + nt * 16]; }

  // state in registers, MFMA C-layout: st[mt][nt][r] = state[mt*16+lq*4+r][cb+nt*16+lh]
  f32x4 st[4][4];
#pragma unroll
  for (int mt = 0; mt < 4; ++mt)
#pragma unroll
    for (int nt = 0; nt < 4; ++nt) {
#pragma unroll
      for (int r = 0; r < 4; ++r)
        st[mt][nt][r] = latent[(size_t)(rowBase + mt * 16 + lq * 4 + r) * HID + cbl + nt * 16];
    }

  // prologue warm: W1 for step 0
  warm_w(W1bf, warm_scratch, bid, w, l);

  // write X_0 = state + pe[0]
  {
    float pev[4];
#pragma unroll
    for (int nt = 0; nt < 4; ++nt) pev[nt] = pos[cbl + nt * 16];
#pragma unroll
    for (int mt = 0; mt < 4; ++mt)
#pragma unroll
      for (int nt = 0; nt < 4; ++nt)
#pragma unroll
        for (int r = 0; r < 4; ++r) {
          int row = mt * 16 + lq * 4 + r;
          int idx = ((row << 9) + cbl + nt * 16) ^ ((row & 7) << 3);
          Xs[idx] = f2bf(st[mt][nt][r] + pev[nt]);
        }
  }
  __syncthreads();

  const unsigned short* woutp = Woutbf + lh * HID + lq * 8;

  for (int t = 0; t < T_STEPS; ++t) {
    // warm W2 (used ~10us from now in GEMM2) -- overlaps GEMM1
    warm_w(W2bf, warm_scratch, bid, w, l);

    // ---- GEMM1: a1 = X_t * W1^T + b1 ----
    f32x4 a1[4][4];
#pragma unroll
    for (int mt = 0; mt < 4; ++mt)
#pragma unroll
      for (int nt = 0; nt < 4; ++nt)
        a1[mt][nt] = (f32x4){b1v[nt], b1v[nt], b1v[nt], b1v[nt]};
    gemm_tile(Xs, W1bf, a1, cb, lh, lq, abase, axor);

    // ---- gelu -> Hs ----
#pragma unroll
    for (int mt = 0; mt < 4; ++mt)
#pragma unroll
      for (int nt = 0; nt < 4; ++nt)
#pragma unroll
        for (int r = 0; r < 4; ++r) {
          float g = gelu_f(a1[mt][nt][r]);
          int row = mt * 16 + lq * 4 + r;
          int idx = ((row << 9) + cbl + nt * 16) ^ ((row & 7) << 3);
          Hs[idx] = f2bf(g);
        }
    __syncthreads();

    // warm next step's W1 -- overlaps GEMM2
    warm_w(W1bf, warm_scratch, bid, w, l);

    // ---- GEMM2: st = st + h * W2^T + b2  (residual accumulates in-place) ----
#pragma unroll
    for (int mt = 0; mt < 4; ++mt)
#pragma unroll
      for (int nt = 0; nt < 4; ++nt)
        st[mt][nt] += b2v[nt];
    gemm_tile(Hs, W2bf, st, cb, lh, lq, abase, axor);

    // ---- write X_{t+1} = state_t + pe[t+1]  (pe=0 for last step) ----
    {
      float pev[4] = {0.f, 0.f, 0.f, 0.f};
      if (t < T_STEPS - 1) {
#pragma unroll
        for (int nt = 0; nt < 4; ++nt) pev[nt] = pos[(t + 1) * HID + cbl + nt * 16];
      }
#pragma unroll
      for (int mt = 0; mt < 4; ++mt)
#pragma unroll
        for (int nt = 0; nt < 4; ++nt)
#pragma unroll
          for (int r = 0; r < 4; ++r) {
            int row = mt * 16 + lq * 4 + r;
            int idx = ((row << 9) + cbl + nt * 16) ^ ((row & 7) << 3);
            Xs[idx] = f2bf(st[mt][nt][r] + pev[nt]);
          }
    }
    __syncthreads();

    // ---- out-proj (waves 0-3) overlapped with global alignment barrier (wave 7) ----
    if (w < 4) {
      const int mt = w;
      float cv = corr[t * 16 + lh];
      f32x4 ao = {cv, cv, cv, cv};
#pragma unroll
      for (int kk = 0; kk < 16; ++kk) {
        short8 af = *(const short8*)(Xs + (((mt * 8192) + abase + kk * 32) ^ axor));
        short8 bfr = *(const short8*)(woutp + kk * 32);
        ao = __builtin_amdgcn_mfma_f32_16x16x32_bf16(af, bfr, ao, 0, 0, 0);
      }
#pragma unroll
      for (int r = 0; r < 4; ++r) {
        int row = rowBase + mt * 16 + lq * 4 + r;
        int bb = row >> 8, ss = row & 255;
        out[(size_t)((bb * T_STEPS + t) * 256 + ss) * 16 + lh] = ao[r];
      }
    } else if (tid == 448) {
      // Global alignment barrier: monotonic counter; purely a scheduling device
      // (no data crosses it) -- relaxed atomics + bounded spin, cannot deadlock.
      unsigned int target = 256u * (unsigned int)(t + 1);
      __hip_atomic_fetch_add(gbar, 1u, __ATOMIC_RELAXED, __HIP_MEMORY_SCOPE_AGENT);
      for (int p = 0; p < 2000; ++p) {
        unsigned int v = __hip_atomic_load(gbar, __ATOMIC_RELAXED, __HIP_MEMORY_SCOPE_AGENT);
        if (v >= target) break;
        __builtin_amdgcn_s_sleep(4);
      }
    }
    __syncthreads();
  }
}

extern "C" void kernel_launch(void* const* d_in, const int* in_sizes, int n_in,
                              void* d_out, int out_size, void* d_ws, size_t ws_size,
                              hipStream_t stream) {
  const float* latent = (const float*)d_in[0];
  const float* W1 = (const float*)d_in[1];
  const float* b1 = (const float*)d_in[2];
  const float* W2 = (const float*)d_in[3];
  const float* b2 = (const float*)d_in[4];
  const float* Wout = (const float*)d_in[5];
  const float* bout = (const float*)d_in[6];
  const float* pos = (const float*)d_in[7];

  unsigned short* wbf = (unsigned short*)d_ws;
  unsigned short* W1bf = wbf;                     // 512*512
  unsigned short* W2bf = wbf + 262144;            // 512*512
  unsigned short* Woutbf = wbf + 524288;          // 16*512
  float* corr = (float*)(wbf + 532480);           // 90*16 floats @ byte 1064960
  unsigned int* gbar = (unsigned int*)((char*)d_ws + 1070720);

  hipMemsetAsync(gbar, 0, 4, stream);  // deterministic per launch/replay
  prep_convert<<<2080, 256, 0, stream>>>(W1, W2, Wout, wbf);
  prep_corr<<<6, 256, 0, stream>>>(pos, bout, Woutbf, corr);
  fd_main<<<NBLK, 512, 0, stream>>>(latent, b1, b2, pos, W1bf, W2bf, Woutbf, corr,
                                    gbar, (float*)d_out);
}